// Round 13
// baseline (564.115 us; speedup 1.0000x reference)
//
#include <hip/hip_runtime.h>

typedef __attribute__((ext_vector_type(8))) short s8v;
typedef __attribute__((ext_vector_type(4))) float f4v;
typedef __attribute__((ext_vector_type(4))) unsigned short us4v;
typedef __attribute__((ext_vector_type(8))) unsigned short us8v;

#define MFMA(a, b, c) __builtin_amdgcn_mfma_f32_16x16x32_bf16(a, b, c, 0, 0, 0)
#define GLOAD16(g, l)                                                          \
  __builtin_amdgcn_global_load_lds((const __attribute__((address_space(1))) void*)(g), \
                                   (__attribute__((address_space(3))) void*)(l), 16, 0, 0)

#define L2E 1.44269504088896f
#define C128L2E 184.6649652337873f   // 128 * log2(e)

__device__ __forceinline__ unsigned short f2bf(float x) {
  unsigned int u = __float_as_uint(x);
  u += 0x7fffu + ((u >> 16) & 1u);   // round-to-nearest-even
  return (unsigned short)(u >> 16);
}
__device__ __forceinline__ float bf2f(unsigned short h) {
  return __uint_as_float(((unsigned int)h) << 16);
}

// ---------------- zero accumulators ----------------
__global__ void k_zero(float* p, int n) {
  int i = blockIdx.x * 256 + threadIdx.x;
  if (i < n) p[i] = 0.f;
}

// ---------------- W -> bf16 (pad 800 -> 896 rows) ----------------
__global__ __launch_bounds__(256) void k_wbf(const float* __restrict__ W,
                                             unsigned short* __restrict__ wb) {
  int idx = blockIdx.x * 256 + threadIdx.x;     // < 896*1024
  int f = idx >> 10;
  wb[idx] = f2bf((f < 800) ? W[idx] : 0.f);
}

// ---- prep: fp32 [8192][1024] -> bf16 row-major [8192][1024] AND bf16 transposed [1024][8192]
__global__ __launch_bounds__(256) void k_prep(const float* __restrict__ in,
                                              unsigned short* __restrict__ outb,
                                              unsigned short* __restrict__ outT) {
  __shared__ float lf[64 * 68];
  int bx = blockIdx.x;
  int rb = bx >> 4, cb = bx & 15;
  long r0 = (long)rb * 64, c0 = (long)cb * 64;
  int tid = threadIdx.x;
#pragma unroll
  for (int q = 0; q < 4; ++q) {
    int fid = tid + 256 * q;
    int r = fid >> 4, c4 = fid & 15;
    f4v v = *(const f4v*)&in[(r0 + r) * 1024 + c0 + 4 * c4];
    *(f4v*)&lf[r * 68 + 4 * c4] = v;
    us4v h;
#pragma unroll
    for (int e = 0; e < 4; ++e) h[e] = f2bf(v[e]);
    *(us4v*)&outb[(r0 + r) * 1024 + c0 + 4 * c4] = h;
  }
  __syncthreads();
#pragma unroll
  for (int q = 0; q < 4; ++q) {
    int fid = tid + 256 * q;
    int oc = fid >> 4, or4 = fid & 15;
    us4v h;
#pragma unroll
    for (int e = 0; e < 4; ++e) h[e] = f2bf(lf[(4 * or4 + e) * 68 + oc]);
    *(us4v*)&outT[(c0 + oc) * 8192 + r0 + 4 * or4] = h;
  }
}

// ----- raw GEMM + softmax-exp fusion: Pb = bf16(exp(m1@m2^T - 128)), plus
//       row/col exp-sum partials. 256x256 tile, BK=32, 4 bufs, 1 barrier/K-tile.
//       ds_read->MFMA scheduling left to the compiler (fine-grained lgkmcnt). -----
__global__ __launch_bounds__(512, 2) void k_gemm_raw8(const unsigned short* __restrict__ m1b,
                                                      const unsigned short* __restrict__ m2b,
                                                      unsigned short* __restrict__ Pb,
                                                      float* __restrict__ row_s,
                                                      float* __restrict__ col_s) {
  __shared__ unsigned short LDS[65536];   // 4 bufs x (A 256x32 | B 256x32) = 128 KiB
  const int tid = threadIdx.x, lane = tid & 63, wid = tid >> 6;
  const int wr = wid >> 2, wc = wid & 3;  // 2 x 4 wave grid, 128x64 output each
  const int x = lane >> 4;

  int swz = ((int)blockIdx.x & 7) * 128 + ((int)blockIdx.x >> 3);
  const long i0 = (long)(swz >> 5) * 256;
  const long j0 = (long)(swz & 31) * 256;

  const unsigned short* gA[2];
  const unsigned short* gB[2];
  int ldst[2];
#pragma unroll
  for (int s = 0; s < 2; ++s) {
    int c = s * 512 + tid;              // r = c>>2 (row), qp = c&3 (16B slot)
    int r = c >> 2, qp = c & 3;
    int ql = qp ^ ((r >> 1) & 3);
    gA[s] = m1b + (i0 + r) * 1024 + ql * 8;
    gB[s] = m2b + (j0 + r) * 1024 + ql * 8;
    ldst[s] = c * 8;
  }
  int offA[8], offB[4];
#pragma unroll
  for (int m = 0; m < 8; ++m) {
    int rr = wr * 128 + m * 16 + (lane & 15);
    offA[m] = (rr * 4 + (x ^ ((rr >> 1) & 3))) * 8;
  }
#pragma unroll
  for (int n = 0; n < 4; ++n) {
    int cc = wc * 64 + n * 16 + (lane & 15);
    offB[n] = (cc * 4 + (x ^ ((cc >> 1) & 3))) * 8;
  }

  f4v acc[8][4];
#pragma unroll
  for (int m = 0; m < 8; ++m)
#pragma unroll
    for (int n = 0; n < 4; ++n) acc[m][n] = (f4v)0.f;

#define STG(u, kt)                                                            \
  do {                                                                        \
    _Pragma("unroll") for (int s = 0; s < 2; ++s)                             \
        GLOAD16(gA[s] + (kt) * 32, &LDS[(u) * 16384 + ldst[s]]);              \
    _Pragma("unroll") for (int s = 0; s < 2; ++s)                             \
        GLOAD16(gB[s] + (kt) * 32, &LDS[(u) * 16384 + 8192 + ldst[s]]);       \
  } while (0)

  STG(0, 0); STG(1, 1); STG(2, 2);

  for (int kt = 0; kt < 32; ++kt) {
    const int u = kt & 3;
    if (kt < 30)      asm volatile("s_waitcnt vmcnt(8)" ::: "memory");
    else if (kt == 30) asm volatile("s_waitcnt vmcnt(4)" ::: "memory");
    else               asm volatile("s_waitcnt vmcnt(0)" ::: "memory");
    asm volatile("s_barrier" ::: "memory");
    if (kt < 29) STG((kt + 3) & 3, kt + 3);   // issue next stage early (buf freed by barrier)
    const int Ab = u * 16384, Bb = u * 16384 + 8192;
    s8v af[8], bf[4];
#pragma unroll
    for (int m = 0; m < 8; ++m) af[m] = *(const s8v*)&LDS[Ab + offA[m]];
#pragma unroll
    for (int n = 0; n < 4; ++n) bf[n] = *(const s8v*)&LDS[Bb + offB[n]];
    __builtin_amdgcn_s_setprio(1);
#pragma unroll
    for (int m = 0; m < 8; ++m)
#pragma unroll
      for (int n = 0; n < 4; ++n)
        acc[m][n] = MFMA(af[m], bf[n], acc[m][n]);
    __builtin_amdgcn_s_setprio(0);
  }
#undef STG

  // ---- fused epilogue: Pb = bf16(exp(v-128)) + row/col partial sums ----
  float* rsf = (float*)LDS;
  float* csf = rsf + 256;
  if (tid < 256) { rsf[tid] = 0.f; csf[tid] = 0.f; }
  __syncthreads();
  float cls[4] = {0.f, 0.f, 0.f, 0.f};
#pragma unroll
  for (int m = 0; m < 8; ++m) {
    long rbase = i0 + wr * 128 + m * 16 + x * 4;
#pragma unroll
    for (int r = 0; r < 4; ++r) {
      float rsum = 0.f;
#pragma unroll
      for (int n = 0; n < 4; ++n) {
        long col = j0 + wc * 64 + n * 16 + (lane & 15);
        float e = exp2f(fmaf(acc[m][n][r], L2E, -C128L2E));  // exp(v - 128)
        Pb[(rbase + r) * 8192 + col] = f2bf(e);
        rsum += e;
        cls[n] += e;
      }
      rsum += __shfl_xor(rsum, 1);
      rsum += __shfl_xor(rsum, 2);
      rsum += __shfl_xor(rsum, 4);
      rsum += __shfl_xor(rsum, 8);
      if ((lane & 15) == 0)
        atomicAdd(&rsf[wr * 128 + m * 16 + x * 4 + r], rsum);
    }
  }
#pragma unroll
  for (int n = 0; n < 4; ++n) {
    cls[n] += __shfl_xor(cls[n], 16);
    cls[n] += __shfl_xor(cls[n], 32);
    if (lane < 16) atomicAdd(&csf[wc * 64 + n * 16 + lane], cls[n]);
  }
  __syncthreads();
  if (tid < 256) {
    atomicAdd(&row_s[i0 + tid], rsf[tid]);
    atomicAdd(&col_s[j0 + tid], csf[tid]);
  }
}

// ----- att = (P @ B^T) / div : 256x128 tile, BK=32, 4 bufs, 3-deep, 1 barrier/K-tile -----
__global__ __launch_bounds__(512, 2) void k_gemm_att8(const unsigned short* __restrict__ P,
                                                      const unsigned short* __restrict__ BT,
                                                      unsigned short* __restrict__ attb,
                                                      float* __restrict__ meanv,
                                                      const float* __restrict__ divv) {
  __shared__ unsigned short LDS[49152];   // 4 bufs x (A 256x32 | B 128x32) = 96 KiB
  const int tid = threadIdx.x, lane = tid & 63, wid = tid >> 6;
  const int wr = wid >> 1, wc = wid & 1;  // 4x2 wave grid, 64x64 output each
  const int x = lane >> 4;

  int swz = ((int)blockIdx.x & 7) * 32 + ((int)blockIdx.x >> 3);
  const long i0 = (long)(swz >> 3) * 256;
  const long d0 = (long)(swz & 7) * 128;

  const unsigned short* gA[2];
  const unsigned short* gB0;
  int ldstA[2], ldstB0;
#pragma unroll
  for (int s = 0; s < 2; ++s) {
    int c = s * 512 + tid;
    int r = c >> 2, qp = c & 3;
    int ql = qp ^ ((r >> 1) & 3);
    gA[s] = P + (i0 + r) * 8192 + ql * 8;
    ldstA[s] = c * 8;
  }
  {
    int c = tid;                        // B: 128 rows x 4 chunks = 512
    int r = c >> 2, qp = c & 3;
    int ql = qp ^ ((r >> 1) & 3);
    gB0 = BT + (d0 + r) * 8192 + ql * 8;
    ldstB0 = c * 8;
  }
  int offA[4], offB[4];
#pragma unroll
  for (int m = 0; m < 4; ++m) {
    int rr = wr * 64 + m * 16 + (lane & 15);
    offA[m] = (rr * 4 + (x ^ ((rr >> 1) & 3))) * 8;
  }
#pragma unroll
  for (int n = 0; n < 4; ++n) {
    int cc = wc * 64 + n * 16 + (lane & 15);
    offB[n] = (cc * 4 + (x ^ ((cc >> 1) & 3))) * 8;
  }

  f4v acc[4][4];
#pragma unroll
  for (int m = 0; m < 4; ++m)
#pragma unroll
    for (int n = 0; n < 4; ++n) acc[m][n] = (f4v)0.f;

#define STGA(u, kt)                                                           \
  do {                                                                        \
    _Pragma("unroll") for (int s = 0; s < 2; ++s)                             \
        GLOAD16(gA[s] + (kt) * 32, &LDS[(u) * 12288 + ldstA[s]]);             \
    GLOAD16(gB0 + (kt) * 32, &LDS[(u) * 12288 + 8192 + ldstB0]);              \
  } while (0)

  STGA(0, 0); STGA(1, 1); STGA(2, 2);

  for (int kt = 0; kt < 256; ++kt) {
    const int u = kt & 3;
    if (kt < 254)       asm volatile("s_waitcnt vmcnt(6)" ::: "memory");
    else if (kt == 254) asm volatile("s_waitcnt vmcnt(3)" ::: "memory");
    else                asm volatile("s_waitcnt vmcnt(0)" ::: "memory");
    asm volatile("s_barrier" ::: "memory");
    if (kt < 253) STGA((kt + 3) & 3, kt + 3);
    const int Ab = u * 12288, Bb = u * 12288 + 8192;
    s8v af[4], bf[4];
#pragma unroll
    for (int m = 0; m < 4; ++m) af[m] = *(const s8v*)&LDS[Ab + offA[m]];
#pragma unroll
    for (int n = 0; n < 4; ++n) bf[n] = *(const s8v*)&LDS[Bb + offB[n]];
    __builtin_amdgcn_s_setprio(1);
#pragma unroll
    for (int m = 0; m < 4; ++m)
#pragma unroll
      for (int n = 0; n < 4; ++n)
        acc[m][n] = MFMA(af[m], bf[n], acc[m][n]);
    __builtin_amdgcn_s_setprio(0);
  }
#undef STGA

  float inv[4][4];
#pragma unroll
  for (int m = 0; m < 4; ++m)
#pragma unroll
    for (int r = 0; r < 4; ++r)
      inv[m][r] = 1.f / divv[i0 + wr * 64 + m * 16 + x * 4 + r];

#pragma unroll
  for (int n = 0; n < 4; ++n) {
    long colg = d0 + wc * 64 + n * 16 + (lane & 15);
    float s = 0.f;
#pragma unroll
    for (int m = 0; m < 4; ++m) {
      long rowg = i0 + wr * 64 + m * 16 + x * 4;
      f4v a = acc[m][n];
#pragma unroll
      for (int r = 0; r < 4; ++r) {
        float val = a[r] * inv[m][r];
        attb[(rowg + r) * 1024 + colg] = f2bf(val);
        s += val;
      }
    }
    s += __shfl_xor(s, 16);
    s += __shfl_xor(s, 32);
    if (lane < 16) atomicAdd(&meanv[d0 + wc * 64 + n * 16 + lane], s);
  }
}

// ------- k_tr: in-place bf16 8192x8192 transpose (tile-pair swap) ---------
__global__ __launch_bounds__(256) void k_tr(unsigned short* buf) {
  __shared__ unsigned short lt[2][64 * 80];
  int a = blockIdx.x >> 7, b = blockIdx.x & 127;
  if (a > b) return;
  const int tid = threadIdx.x;
  const int r = tid & 63;
  const int cw = tid >> 6;
  const int ntile = (a == b) ? 1 : 2;

  for (int t = 0; t < ntile; ++t) {
    long ro = (long)(t == 0 ? a : b) * 64;
    long co = (long)(t == 0 ? b : a) * 64;
#pragma unroll
    for (int q = 0; q < 2; ++q) {
      int c8 = cw + 4 * q;
      us8v u = *(const us8v*)&buf[(ro + r) * 8192 + co + c8 * 8];
#pragma unroll
      for (int e = 0; e < 8; ++e) lt[t][(c8 * 8 + e) * 80 + r] = u[e];
    }
  }
  __syncthreads();
  for (int t = 0; t < ntile; ++t) {
    long dr = (long)(t == 0 ? b : a) * 64;
    long dc = (long)(t == 0 ? a : b) * 64;
#pragma unroll
    for (int q = 0; q < 2; ++q) {
      int fid = tid + 256 * q;
      int jr = fid >> 3, c8 = fid & 7;
      us8v o = *(const us8v*)&lt[t][jr * 80 + c8 * 8];
      *(us8v*)&buf[(dr + jr) * 8192 + dc + c8 * 8] = o;
    }
  }
}

// ---------------- tanh(att @ W^T + b) column sums (glds) ------------
__global__ __launch_bounds__(256) void k_gemm_tanh(const unsigned short* __restrict__ attb,
                                                   const unsigned short* __restrict__ Wb,
                                                   const float* __restrict__ bias,
                                                   float* __restrict__ acct) {
  __shared__ unsigned short As[128 * 32], Bs[128 * 32];
  const int tid = threadIdx.x, lane = tid & 63, wv = tid >> 6;
  const int wrow = wv >> 1, wcol = wv & 1;
  int sw = ((int)blockIdx.x & 7) * 56 + ((int)blockIdx.x >> 3);
  const long i0 = (long)(sw / 7) * 128;
  const long f0 = (long)(sw % 7) * 128;

  const int r16 = lane >> 2;
  const int sslot = (lane & 3) ^ ((r16 >> 1) & 3);
  const unsigned short* gA0 = &attb[(i0 + 32 * wv + r16) * 1024 + sslot * 8];
  const unsigned short* gA1 = gA0 + 16 * 1024;
  const unsigned short* gB0 = &Wb[(f0 + 32 * wv + r16) * 1024 + sslot * 8];
  const unsigned short* gB1 = gB0 + 16 * 1024;
  unsigned short* lA0 = &As[(32 * wv) * 32];
  unsigned short* lA1 = &As[(32 * wv + 16) * 32];
  unsigned short* lB0 = &Bs[(32 * wv) * 32];
  unsigned short* lB1 = &Bs[(32 * wv + 16) * 32];

  f4v acc[4][4];
#pragma unroll
  for (int a = 0; a < 4; ++a)
#pragma unroll
    for (int b = 0; b < 4; ++b) acc[a][b] = (f4v)0.f;

  for (int kt = 0; kt < 32; ++kt) {
    GLOAD16(gA0 + kt * 32, lA0);
    GLOAD16(gA1 + kt * 32, lA1);
    GLOAD16(gB0 + kt * 32, lB0);
    GLOAD16(gB1 + kt * 32, lB1);
    __syncthreads();
    const int kkx = lane >> 4;
    s8v af[4], bf[4];
#pragma unroll
    for (int mf = 0; mf < 4; ++mf) {
      int rr = wrow * 64 + mf * 16 + (lane & 15);
      af[mf] = *(const s8v*)&As[rr * 32 + (kkx ^ ((rr >> 1) & 3)) * 8];
      int cc = wcol * 64 + mf * 16 + (lane & 15);
      bf[mf] = *(const s8v*)&Bs[cc * 32 + (kkx ^ ((cc >> 1) & 3)) * 8];
    }
#pragma unroll
    for (int mf = 0; mf < 4; ++mf)
#pragma unroll
      for (int nf = 0; nf < 4; ++nf)
        acc[mf][nf] = MFMA(af[mf], bf[nf], acc[mf][nf]);
    __syncthreads();
  }
#pragma unroll
  for (int nf = 0; nf < 4; ++nf) {
    long colg = f0 + wcol * 64 + nf * 16 + (lane & 15);
    float bv = (colg < 800) ? bias[colg] : 0.f;
    float s = 0.f;
#pragma unroll
    for (int mf = 0; mf < 4; ++mf) {
      f4v a = acc[mf][nf];
#pragma unroll
      for (int r = 0; r < 4; ++r) s += tanhf(a[r] + bv);
    }
    s += __shfl_xor(s, 16);
    s += __shfl_xor(s, 32);
    if (lane < 16) atomicAdd(&acct[f0 + wcol * 64 + nf * 16 + lane], s);
  }
}

// ---------------- filters: sigmoid(mean_att . Wf + bf) ----------------
__global__ __launch_bounds__(256) void k_filt(const float* __restrict__ Wf1,
                                              const float* __restrict__ bf1,
                                              const float* __restrict__ Wf2,
                                              const float* __restrict__ bf2,
                                              const float* __restrict__ mean2,
                                              const float* __restrict__ mean1,
                                              float* __restrict__ filt1,
                                              float* __restrict__ filt2) {
  int wv = threadIdx.x >> 6, lane = threadIdx.x & 63;
  int gid = blockIdx.x * 4 + wv;  // 0..1599
  const float* Wr;
  const float* mv;
  float b;
  float* outp;
  if (gid < 800) {
    Wr = Wf1 + (long)gid * 1024; mv = mean2; b = bf1[gid]; outp = filt1 + gid;
  } else {
    int f = gid - 800;
    Wr = Wf2 + (long)f * 1024; mv = mean1; b = bf2[f]; outp = filt2 + f;
  }
  float s = 0.f;
#pragma unroll
  for (int q = 0; q < 16; ++q) s += mv[lane + 64 * q] * Wr[lane + 64 * q];
#pragma unroll
  for (int off = 32; off >= 1; off >>= 1) s += __shfl_xor(s, off);
  if (lane == 0) *outp = 1.f / (1.f + __expf(-(s * (1.f / 8192.f) + b)));
}

// ---------------- final combine ----------------
__global__ void k_final(const float* __restrict__ acct1, const float* __restrict__ acct2,
                        const float* __restrict__ filt1, const float* __restrict__ filt2,
                        float* __restrict__ out) {
  int i = blockIdx.x * 256 + threadIdx.x;
  if (i < 800) {
    out[i] = acct1[i] * (1.f / 8192.f) * filt1[i];
    out[800 + i] = acct2[i] * (1.f / 8192.f) * filt2[i];
  }
}

extern "C" void kernel_launch(void* const* d_in, const int* in_sizes, int n_in,
                              void* d_out, int out_size, void* d_ws, size_t ws_size,
                              hipStream_t stream) {
  (void)in_sizes; (void)n_in; (void)out_size;
  const float* m1  = (const float*)d_in[0];
  const float* m2  = (const float*)d_in[1];
  const float* Wf1 = (const float*)d_in[2];
  const float* bf1 = (const float*)d_in[3];
  const float* Wf2 = (const float*)d_in[4];
  const float* bf2 = (const float*)d_in[5];
  const float* W1  = (const float*)d_in[6];
  const float* b1  = (const float*)d_in[7];
  const float* W2  = (const float*)d_in[8];
  const float* b2  = (const float*)d_in[9];
  float* out = (float*)d_out;
  char* ws = (char*)d_ws;

  // ws layout (ends < 207246592 B; same guard as before)
  unsigned short* Pb   = (unsigned short*)(ws);                 // 134217728: P~ = bf16(exp(raw-128)), transposed in place later
  unsigned short* m1T  = (unsigned short*)(ws + 134217728UL);   // 16777216
  unsigned short* m2T  = (unsigned short*)(ws + 150994944UL);   // 16777216
  unsigned short* m1b  = (unsigned short*)(ws + 167772160UL);   // 16777216 (overlaid by att1)
  unsigned short* m2b  = (unsigned short*)(ws + 184549376UL);   // 16777216 (overlaid by att2)
  unsigned short* att1 = (unsigned short*)(ws + 167772160UL);   // overlay: m1b dead after raw GEMM
  unsigned short* att2 = (unsigned short*)(ws + 184549376UL);   // overlay: m2b dead after raw GEMM
  unsigned short* W1b  = (unsigned short*)(ws + 201326592UL);   // 1835008
  unsigned short* W2b  = (unsigned short*)(ws + 203161600UL);   // 1835008
  float* row_s = (float*)(ws + 205062144UL);   // 32768   (row_s..acct2 zeroed together)
  float* col_s = (float*)(ws + 205094912UL);   // 32768
  float* mean1 = (float*)(ws + 205127680UL);   // 4096
  float* mean2 = (float*)(ws + 205131776UL);   // 4096
  float* acct1 = (float*)(ws + 205135872UL);   // 4096
  float* acct2 = (float*)(ws + 205139968UL);   // 4096
  float* filt1 = (float*)(ws + 205144064UL);   // 4096
  float* filt2 = (float*)(ws + 205148160UL);   // 3200

  // Diagnostic guard: if ws is too small, do nothing -> harness reports the
  // stub absmax (1.73e-2) instead of a GPU memory fault.
  if (ws_size < 207246592UL) return;

  k_zero<<<80, 256, 0, stream>>>(row_s, 20480);  // row_s col_s mean1 mean2 acct1 acct2
  k_wbf<<<3584, 256, 0, stream>>>(W1, W1b);
  k_wbf<<<3584, 256, 0, stream>>>(W2, W2b);
  k_prep<<<2048, 256, 0, stream>>>(m1, m1b, m1T);
  k_prep<<<2048, 256, 0, stream>>>(m2, m2b, m2T);
  k_gemm_raw8<<<1024, 512, 0, stream>>>(m1b, m2b, Pb, row_s, col_s);
  k_gemm_att8<<<256, 512, 0, stream>>>(Pb, m2T, att2, mean2, row_s);   // att2 = (P~ @ m2)/row_s
  k_tr<<<16384, 256, 0, stream>>>(Pb);                                 // P~ -> P~^T in place
  k_gemm_att8<<<256, 512, 0, stream>>>(Pb, m1T, att1, mean1, col_s);   // att1 = (P~^T @ m1)/col_s
  k_gemm_tanh<<<448, 256, 0, stream>>>(att1, W1b, b1, acct1);
  k_gemm_tanh<<<448, 256, 0, stream>>>(att2, W2b, b2, acct2);
  k_filt<<<400, 256, 0, stream>>>(Wf1, bf1, Wf2, bf2, mean2, mean1, filt1, filt2);
  k_final<<<4, 256, 0, stream>>>(acct1, acct2, filt1, filt2, out);
}

// Round 14
// 539.818 us; speedup vs baseline: 1.0450x; 1.0450x over previous
//
#include <hip/hip_runtime.h>

typedef __attribute__((ext_vector_type(8))) short s8v;
typedef __attribute__((ext_vector_type(4))) float f4v;
typedef __attribute__((ext_vector_type(4))) unsigned short us4v;
typedef __attribute__((ext_vector_type(8))) unsigned short us8v;

#define MFMA(a, b, c) __builtin_amdgcn_mfma_f32_16x16x32_bf16(a, b, c, 0, 0, 0)
#define GLOAD16(g, l)                                                          \
  __builtin_amdgcn_global_load_lds((const __attribute__((address_space(1))) void*)(g), \
                                   (__attribute__((address_space(3))) void*)(l), 16, 0, 0)

#define L2E 1.44269504088896f
#define C128L2E 184.6649652337873f   // 128 * log2(e)

__device__ __forceinline__ unsigned short f2bf(float x) {
  unsigned int u = __float_as_uint(x);
  u += 0x7fffu + ((u >> 16) & 1u);   // round-to-nearest-even
  return (unsigned short)(u >> 16);
}
__device__ __forceinline__ float bf2f(unsigned short h) {
  return __uint_as_float(((unsigned int)h) << 16);
}

// ---------------- zero accumulators ----------------
__global__ void k_zero(float* p, int n) {
  int i = blockIdx.x * 256 + threadIdx.x;
  if (i < n) p[i] = 0.f;
}

// ---------------- W -> bf16 (pad 800 -> 896 rows) ----------------
__global__ __launch_bounds__(256) void k_wbf(const float* __restrict__ W,
                                             unsigned short* __restrict__ wb) {
  int idx = blockIdx.x * 256 + threadIdx.x;     // < 896*1024
  int f = idx >> 10;
  wb[idx] = f2bf((f < 800) ? W[idx] : 0.f);
}

// ---- prep: fp32 [8192][1024] -> bf16 row-major [8192][1024] AND bf16 transposed [1024][8192]
__global__ __launch_bounds__(256) void k_prep(const float* __restrict__ in,
                                              unsigned short* __restrict__ outb,
                                              unsigned short* __restrict__ outT) {
  __shared__ float lf[64 * 68];
  int bx = blockIdx.x;
  int rb = bx >> 4, cb = bx & 15;
  long r0 = (long)rb * 64, c0 = (long)cb * 64;
  int tid = threadIdx.x;
#pragma unroll
  for (int q = 0; q < 4; ++q) {
    int fid = tid + 256 * q;
    int r = fid >> 4, c4 = fid & 15;
    f4v v = *(const f4v*)&in[(r0 + r) * 1024 + c0 + 4 * c4];
    *(f4v*)&lf[r * 68 + 4 * c4] = v;
    us4v h;
#pragma unroll
    for (int e = 0; e < 4; ++e) h[e] = f2bf(v[e]);
    *(us4v*)&outb[(r0 + r) * 1024 + c0 + 4 * c4] = h;
  }
  __syncthreads();
#pragma unroll
  for (int q = 0; q < 4; ++q) {
    int fid = tid + 256 * q;
    int oc = fid >> 4, or4 = fid & 15;
    us4v h;
#pragma unroll
    for (int e = 0; e < 4; ++e) h[e] = f2bf(lf[(4 * or4 + e) * 68 + oc]);
    *(us4v*)&outT[(c0 + oc) * 8192 + r0 + 4 * or4] = h;
  }
}

// ----- raw GEMM + softmax-exp fusion: Pb = bf16(exp(m1@m2^T - 128)), plus
//       row/col exp-sum partials. 256x256 tile, BK=32, 4 bufs, 1 barrier/K-tile. -----
__global__ __launch_bounds__(512, 2) void k_gemm_raw8(const unsigned short* __restrict__ m1b,
                                                      const unsigned short* __restrict__ m2b,
                                                      unsigned short* __restrict__ Pb,
                                                      float* __restrict__ row_s,
                                                      float* __restrict__ col_s) {
  __shared__ unsigned short LDS[65536];   // 4 bufs x (A 256x32 | B 256x32) = 128 KiB
  const int tid = threadIdx.x, lane = tid & 63, wid = tid >> 6;
  const int wr = wid >> 2, wc = wid & 3;  // 2 x 4 wave grid, 128x64 output each
  const int x = lane >> 4;

  int swz = ((int)blockIdx.x & 7) * 128 + ((int)blockIdx.x >> 3);
  const long i0 = (long)(swz >> 5) * 256;
  const long j0 = (long)(swz & 31) * 256;

  const unsigned short* gA[2];
  const unsigned short* gB[2];
  int ldst[2];
#pragma unroll
  for (int s = 0; s < 2; ++s) {
    int c = s * 512 + tid;              // r = c>>2 (row), qp = c&3 (16B slot)
    int r = c >> 2, qp = c & 3;
    int ql = qp ^ ((r >> 1) & 3);
    gA[s] = m1b + (i0 + r) * 1024 + ql * 8;
    gB[s] = m2b + (j0 + r) * 1024 + ql * 8;
    ldst[s] = c * 8;
  }
  int offA[8], offB[4];
#pragma unroll
  for (int m = 0; m < 8; ++m) {
    int rr = wr * 128 + m * 16 + (lane & 15);
    offA[m] = (rr * 4 + (x ^ ((rr >> 1) & 3))) * 8;
  }
#pragma unroll
  for (int n = 0; n < 4; ++n) {
    int cc = wc * 64 + n * 16 + (lane & 15);
    offB[n] = (cc * 4 + (x ^ ((cc >> 1) & 3))) * 8;
  }

  f4v acc[8][4];
#pragma unroll
  for (int m = 0; m < 8; ++m)
#pragma unroll
    for (int n = 0; n < 4; ++n) acc[m][n] = (f4v)0.f;

#define STG(u, kt)                                                            \
  do {                                                                        \
    _Pragma("unroll") for (int s = 0; s < 2; ++s)                             \
        GLOAD16(gA[s] + (kt) * 32, &LDS[(u) * 16384 + ldst[s]]);              \
    _Pragma("unroll") for (int s = 0; s < 2; ++s)                             \
        GLOAD16(gB[s] + (kt) * 32, &LDS[(u) * 16384 + 8192 + ldst[s]]);       \
  } while (0)

  STG(0, 0); STG(1, 1); STG(2, 2);

  for (int kt = 0; kt < 32; ++kt) {
    const int u = kt & 3;
    if (kt < 30)      asm volatile("s_waitcnt vmcnt(8)" ::: "memory");
    else if (kt == 30) asm volatile("s_waitcnt vmcnt(4)" ::: "memory");
    else               asm volatile("s_waitcnt vmcnt(0)" ::: "memory");
    asm volatile("s_barrier" ::: "memory");
    __builtin_amdgcn_sched_barrier(0);
    const int Ab = u * 16384, Bb = u * 16384 + 8192;
    s8v af[8], bf[4];
#pragma unroll
    for (int m = 0; m < 8; ++m) af[m] = *(const s8v*)&LDS[Ab + offA[m]];
#pragma unroll
    for (int n = 0; n < 4; ++n) bf[n] = *(const s8v*)&LDS[Bb + offB[n]];
    if (kt < 29) STG((kt + 3) & 3, kt + 3);
    asm volatile("s_waitcnt lgkmcnt(0)" ::: "memory");
    __builtin_amdgcn_sched_barrier(0);
    __builtin_amdgcn_s_setprio(1);
#pragma unroll
    for (int m = 0; m < 8; ++m)
#pragma unroll
      for (int n = 0; n < 4; ++n)
        acc[m][n] = MFMA(af[m], bf[n], acc[m][n]);
    __builtin_amdgcn_s_setprio(0);
  }
#undef STG

  // ---- fused epilogue: Pb = bf16(exp(v-128)) + row/col partial sums ----
  // LDS buf0 (bytes 0..2047) free after last barrier (only buf3 read after kt=31).
  float* rsf = (float*)LDS;
  float* csf = rsf + 256;
  if (tid < 256) { rsf[tid] = 0.f; csf[tid] = 0.f; }
  __syncthreads();
  float cls[4] = {0.f, 0.f, 0.f, 0.f};
#pragma unroll
  for (int m = 0; m < 8; ++m) {
    long rbase = i0 + wr * 128 + m * 16 + x * 4;
#pragma unroll
    for (int r = 0; r < 4; ++r) {
      float rsum = 0.f;
#pragma unroll
      for (int n = 0; n < 4; ++n) {
        long col = j0 + wc * 64 + n * 16 + (lane & 15);
        float e = exp2f(fmaf(acc[m][n][r], L2E, -C128L2E));  // exp(v - 128)
        Pb[(rbase + r) * 8192 + col] = f2bf(e);
        rsum += e;
        cls[n] += e;
      }
      rsum += __shfl_xor(rsum, 1);
      rsum += __shfl_xor(rsum, 2);
      rsum += __shfl_xor(rsum, 4);
      rsum += __shfl_xor(rsum, 8);
      if ((lane & 15) == 0)
        atomicAdd(&rsf[wr * 128 + m * 16 + x * 4 + r], rsum);
    }
  }
#pragma unroll
  for (int n = 0; n < 4; ++n) {
    cls[n] += __shfl_xor(cls[n], 16);
    cls[n] += __shfl_xor(cls[n], 32);
    if (lane < 16) atomicAdd(&csf[wc * 64 + n * 16 + lane], cls[n]);
  }
  __syncthreads();
  if (tid < 256) {
    atomicAdd(&row_s[i0 + tid], rsf[tid]);
    atomicAdd(&col_s[j0 + tid], csf[tid]);
  }
}

// ----- att = (P @ B^T) / div : 256x128 tile, BK=32, 4 bufs, 3-deep, 1 barrier/K-tile -----
__global__ __launch_bounds__(512, 2) void k_gemm_att8(const unsigned short* __restrict__ P,
                                                      const unsigned short* __restrict__ BT,
                                                      unsigned short* __restrict__ attb,
                                                      float* __restrict__ meanv,
                                                      const float* __restrict__ divv) {
  __shared__ unsigned short LDS[49152];   // 4 bufs x (A 256x32 | B 128x32) = 96 KiB
  const int tid = threadIdx.x, lane = tid & 63, wid = tid >> 6;
  const int wr = wid >> 1, wc = wid & 1;  // 4x2 wave grid, 64x64 output each
  const int x = lane >> 4;

  int swz = ((int)blockIdx.x & 7) * 32 + ((int)blockIdx.x >> 3);
  const long i0 = (long)(swz >> 3) * 256;
  const long d0 = (long)(swz & 7) * 128;

  const unsigned short* gA[2];
  const unsigned short* gB0;
  int ldstA[2], ldstB0;
#pragma unroll
  for (int s = 0; s < 2; ++s) {
    int c = s * 512 + tid;
    int r = c >> 2, qp = c & 3;
    int ql = qp ^ ((r >> 1) & 3);
    gA[s] = P + (i0 + r) * 8192 + ql * 8;
    ldstA[s] = c * 8;
  }
  {
    int c = tid;                        // B: 128 rows x 4 chunks = 512
    int r = c >> 2, qp = c & 3;
    int ql = qp ^ ((r >> 1) & 3);
    gB0 = BT + (d0 + r) * 8192 + ql * 8;
    ldstB0 = c * 8;
  }
  int offA[4], offB[4];
#pragma unroll
  for (int m = 0; m < 4; ++m) {
    int rr = wr * 64 + m * 16 + (lane & 15);
    offA[m] = (rr * 4 + (x ^ ((rr >> 1) & 3))) * 8;
  }
#pragma unroll
  for (int n = 0; n < 4; ++n) {
    int cc = wc * 64 + n * 16 + (lane & 15);
    offB[n] = (cc * 4 + (x ^ ((cc >> 1) & 3))) * 8;
  }

  f4v acc[4][4];
#pragma unroll
  for (int m = 0; m < 4; ++m)
#pragma unroll
    for (int n = 0; n < 4; ++n) acc[m][n] = (f4v)0.f;

#define STGA(u, kt)                                                           \
  do {                                                                        \
    _Pragma("unroll") for (int s = 0; s < 2; ++s)                             \
        GLOAD16(gA[s] + (kt) * 32, &LDS[(u) * 12288 + ldstA[s]]);             \
    GLOAD16(gB0 + (kt) * 32, &LDS[(u) * 12288 + 8192 + ldstB0]);              \
  } while (0)

  STGA(0, 0); STGA(1, 1); STGA(2, 2);

  for (int kt = 0; kt < 256; ++kt) {
    const int u = kt & 3;
    if (kt < 254)       asm volatile("s_waitcnt vmcnt(6)" ::: "memory");
    else if (kt == 254) asm volatile("s_waitcnt vmcnt(3)" ::: "memory");
    else                asm volatile("s_waitcnt vmcnt(0)" ::: "memory");
    asm volatile("s_barrier" ::: "memory");
    __builtin_amdgcn_sched_barrier(0);
    const int Ab = u * 12288, Bb = u * 12288 + 8192;
    s8v af[4], bf[4];
#pragma unroll
    for (int m = 0; m < 4; ++m) af[m] = *(const s8v*)&LDS[Ab + offA[m]];
#pragma unroll
    for (int n = 0; n < 4; ++n) bf[n] = *(const s8v*)&LDS[Bb + offB[n]];
    if (kt < 253) STGA((kt + 3) & 3, kt + 3);
    asm volatile("s_waitcnt lgkmcnt(0)" ::: "memory");
    __builtin_amdgcn_sched_barrier(0);
    __builtin_amdgcn_s_setprio(1);
#pragma unroll
    for (int m = 0; m < 4; ++m)
#pragma unroll
      for (int n = 0; n < 4; ++n)
        acc[m][n] = MFMA(af[m], bf[n], acc[m][n]);
    __builtin_amdgcn_s_setprio(0);
  }
#undef STGA

  float inv[4][4];
#pragma unroll
  for (int m = 0; m < 4; ++m)
#pragma unroll
    for (int r = 0; r < 4; ++r)
      inv[m][r] = 1.f / divv[i0 + wr * 64 + m * 16 + x * 4 + r];

#pragma unroll
  for (int n = 0; n < 4; ++n) {
    long colg = d0 + wc * 64 + n * 16 + (lane & 15);
    float s = 0.f;
#pragma unroll
    for (int m = 0; m < 4; ++m) {
      long rowg = i0 + wr * 64 + m * 16 + x * 4;
      f4v a = acc[m][n];
#pragma unroll
      for (int r = 0; r < 4; ++r) {
        float val = a[r] * inv[m][r];
        attb[(rowg + r) * 1024 + colg] = f2bf(val);
        s += val;
      }
    }
    s += __shfl_xor(s, 16);
    s += __shfl_xor(s, 32);
    if (lane < 16) atomicAdd(&meanv[d0 + wc * 64 + n * 16 + lane], s);
  }
}

// ------- k_tr: in-place bf16 8192x8192 transpose (tile-pair swap) ---------
__global__ __launch_bounds__(256) void k_tr(unsigned short* buf) {
  __shared__ unsigned short lt[2][64 * 80];
  int a = blockIdx.x >> 7, b = blockIdx.x & 127;
  if (a > b) return;
  const int tid = threadIdx.x;
  const int r = tid & 63;
  const int cw = tid >> 6;
  const int ntile = (a == b) ? 1 : 2;

  for (int t = 0; t < ntile; ++t) {
    long ro = (long)(t == 0 ? a : b) * 64;
    long co = (long)(t == 0 ? b : a) * 64;
#pragma unroll
    for (int q = 0; q < 2; ++q) {
      int c8 = cw + 4 * q;
      us8v u = *(const us8v*)&buf[(ro + r) * 8192 + co + c8 * 8];
#pragma unroll
      for (int e = 0; e < 8; ++e) lt[t][(c8 * 8 + e) * 80 + r] = u[e];
    }
  }
  __syncthreads();
  for (int t = 0; t < ntile; ++t) {
    long dr = (long)(t == 0 ? b : a) * 64;
    long dc = (long)(t == 0 ? a : b) * 64;
#pragma unroll
    for (int q = 0; q < 2; ++q) {
      int fid = tid + 256 * q;
      int jr = fid >> 3, c8 = fid & 7;
      us8v o = *(const us8v*)&lt[t][jr * 80 + c8 * 8];
      *(us8v*)&buf[(dr + jr) * 8192 + dc + c8 * 8] = o;
    }
  }
}

// ---------------- tanh(att @ W^T + b) column sums (glds) ------------
__global__ __launch_bounds__(256) void k_gemm_tanh(const unsigned short* __restrict__ attb,
                                                   const unsigned short* __restrict__ Wb,
                                                   const float* __restrict__ bias,
                                                   float* __restrict__ acct) {
  __shared__ unsigned short As[128 * 32], Bs[128 * 32];
  const int tid = threadIdx.x, lane = tid & 63, wv = tid >> 6;
  const int wrow = wv >> 1, wcol = wv & 1;
  int sw = ((int)blockIdx.x & 7) * 56 + ((int)blockIdx.x >> 3);
  const long i0 = (long)(sw / 7) * 128;
  const long f0 = (long)(sw % 7) * 128;

  const int r16 = lane >> 2;
  const int sslot = (lane & 3) ^ ((r16 >> 1) & 3);
  const unsigned short* gA0 = &attb[(i0 + 32 * wv + r16) * 1024 + sslot * 8];
  const unsigned short* gA1 = gA0 + 16 * 1024;
  const unsigned short* gB0 = &Wb[(f0 + 32 * wv + r16) * 1024 + sslot * 8];
  const unsigned short* gB1 = gB0 + 16 * 1024;
  unsigned short* lA0 = &As[(32 * wv) * 32];
  unsigned short* lA1 = &As[(32 * wv + 16) * 32];
  unsigned short* lB0 = &Bs[(32 * wv) * 32];
  unsigned short* lB1 = &Bs[(32 * wv + 16) * 32];

  f4v acc[4][4];
#pragma unroll
  for (int a = 0; a < 4; ++a)
#pragma unroll
    for (int b = 0; b < 4; ++b) acc[a][b] = (f4v)0.f;

  for (int kt = 0; kt < 32; ++kt) {
    GLOAD16(gA0 + kt * 32, lA0);
    GLOAD16(gA1 + kt * 32, lA1);
    GLOAD16(gB0 + kt * 32, lB0);
    GLOAD16(gB1 + kt * 32, lB1);
    __syncthreads();
    const int kkx = lane >> 4;
    s8v af[4], bf[4];
#pragma unroll
    for (int mf = 0; mf < 4; ++mf) {
      int rr = wrow * 64 + mf * 16 + (lane & 15);
      af[mf] = *(const s8v*)&As[rr * 32 + (kkx ^ ((rr >> 1) & 3)) * 8];
      int cc = wcol * 64 + mf * 16 + (lane & 15);
      bf[mf] = *(const s8v*)&Bs[cc * 32 + (kkx ^ ((cc >> 1) & 3)) * 8];
    }
#pragma unroll
    for (int mf = 0; mf < 4; ++mf)
#pragma unroll
      for (int nf = 0; nf < 4; ++nf)
        acc[mf][nf] = MFMA(af[mf], bf[nf], acc[mf][nf]);
    __syncthreads();
  }
#pragma unroll
  for (int nf = 0; nf < 4; ++nf) {
    long colg = f0 + wcol * 64 + nf * 16 + (lane & 15);
    float bv = (colg < 800) ? bias[colg] : 0.f;
    float s = 0.f;
#pragma unroll
    for (int mf = 0; mf < 4; ++mf) {
      f4v a = acc[mf][nf];
#pragma unroll
      for (int r = 0; r < 4; ++r) s += tanhf(a[r] + bv);
    }
    s += __shfl_xor(s, 16);
    s += __shfl_xor(s, 32);
    if (lane < 16) atomicAdd(&acct[f0 + wcol * 64 + nf * 16 + lane], s);
  }
}

// ---------------- filters: sigmoid(mean_att . Wf + bf) ----------------
__global__ __launch_bounds__(256) void k_filt(const float* __restrict__ Wf1,
                                              const float* __restrict__ bf1,
                                              const float* __restrict__ Wf2,
                                              const float* __restrict__ bf2,
                                              const float* __restrict__ mean2,
                                              const float* __restrict__ mean1,
                                              float* __restrict__ filt1,
                                              float* __restrict__ filt2) {
  int wv = threadIdx.x >> 6, lane = threadIdx.x & 63;
  int gid = blockIdx.x * 4 + wv;  // 0..1599
  const float* Wr;
  const float* mv;
  float b;
  float* outp;
  if (gid < 800) {
    Wr = Wf1 + (long)gid * 1024; mv = mean2; b = bf1[gid]; outp = filt1 + gid;
  } else {
    int f = gid - 800;
    Wr = Wf2 + (long)f * 1024; mv = mean1; b = bf2[f]; outp = filt2 + f;
  }
  float s = 0.f;
#pragma unroll
  for (int q = 0; q < 16; ++q) s += mv[lane + 64 * q] * Wr[lane + 64 * q];
#pragma unroll
  for (int off = 32; off >= 1; off >>= 1) s += __shfl_xor(s, off);
  if (lane == 0) *outp = 1.f / (1.f + __expf(-(s * (1.f / 8192.f) + b)));
}

// ---------------- final combine ----------------
__global__ void k_final(const float* __restrict__ acct1, const float* __restrict__ acct2,
                        const float* __restrict__ filt1, const float* __restrict__ filt2,
                        float* __restrict__ out) {
  int i = blockIdx.x * 256 + threadIdx.x;
  if (i < 800) {
    out[i] = acct1[i] * (1.f / 8192.f) * filt1[i];
    out[800 + i] = acct2[i] * (1.f / 8192.f) * filt2[i];
  }
}

extern "C" void kernel_launch(void* const* d_in, const int* in_sizes, int n_in,
                              void* d_out, int out_size, void* d_ws, size_t ws_size,
                              hipStream_t stream) {
  (void)in_sizes; (void)n_in; (void)out_size;
  const float* m1  = (const float*)d_in[0];
  const float* m2  = (const float*)d_in[1];
  const float* Wf1 = (const float*)d_in[2];
  const float* bf1 = (const float*)d_in[3];
  const float* Wf2 = (const float*)d_in[4];
  const float* bf2 = (const float*)d_in[5];
  const float* W1  = (const float*)d_in[6];
  const float* b1  = (const float*)d_in[7];
  const float* W2  = (const float*)d_in[8];
  const float* b2  = (const float*)d_in[9];
  float* out = (float*)d_out;
  char* ws = (char*)d_ws;

  // ws layout (ends < 207246592 B; same guard as before)
  unsigned short* Pb   = (unsigned short*)(ws);                 // 134217728: P~ = bf16(exp(raw-128)), transposed in place later
  unsigned short* m1T  = (unsigned short*)(ws + 134217728UL);   // 16777216
  unsigned short* m2T  = (unsigned short*)(ws + 150994944UL);   // 16777216
  unsigned short* m1b  = (unsigned short*)(ws + 167772160UL);   // 16777216 (overlaid by att1)
  unsigned short* m2b  = (unsigned short*)(ws + 184549376UL);   // 16777216 (overlaid by att2)
  unsigned short* att1 = (unsigned short*)(ws + 167772160UL);   // overlay: m1b dead after raw GEMM
  unsigned short* att2 = (unsigned short*)(ws + 184549376UL);   // overlay: m2b dead after raw GEMM
  unsigned short* W1b  = (unsigned short*)(ws + 201326592UL);   // 1835008
  unsigned short* W2b  = (unsigned short*)(ws + 203161600UL);   // 1835008
  float* row_s = (float*)(ws + 205062144UL);   // 32768   (row_s..acct2 zeroed together)
  float* col_s = (float*)(ws + 205094912UL);   // 32768
  float* mean1 = (float*)(ws + 205127680UL);   // 4096
  float* mean2 = (float*)(ws + 205131776UL);   // 4096
  float* acct1 = (float*)(ws + 205135872UL);   // 4096
  float* acct2 = (float*)(ws + 205139968UL);   // 4096
  float* filt1 = (float*)(ws + 205144064UL);   // 4096
  float* filt2 = (float*)(ws + 205148160UL);   // 3200

  // Diagnostic guard: if ws is too small, do nothing -> harness reports the
  // stub absmax (1.73e-2) instead of a GPU memory fault.
  if (ws_size < 207246592UL) return;

  k_zero<<<80, 256, 0, stream>>>(row_s, 20480);  // row_s col_s mean1 mean2 acct1 acct2
  k_wbf<<<3584, 256, 0, stream>>>(W1, W1b);
  k_wbf<<<3584, 256, 0, stream>>>(W2, W2b);
  k_prep<<<2048, 256, 0, stream>>>(m1, m1b, m1T);
  k_prep<<<2048, 256, 0, stream>>>(m2, m2b, m2T);
  k_gemm_raw8<<<1024, 512, 0, stream>>>(m1b, m2b, Pb, row_s, col_s);
  k_gemm_att8<<<256, 512, 0, stream>>>(Pb, m2T, att2, mean2, row_s);   // att2 = (P~ @ m2)/row_s
  k_tr<<<16384, 256, 0, stream>>>(Pb);                                 // P~ -> P~^T in place
  k_gemm_att8<<<256, 512, 0, stream>>>(Pb, m1T, att1, mean1, col_s);   // att1 = (P~^T @ m1)/col_s
  k_gemm_tanh<<<448, 256, 0, stream>>>(att1, W1b, b1, acct1);
  k_gemm_tanh<<<448, 256, 0, stream>>>(att2, W2b, b2, acct2);
  k_filt<<<400, 256, 0, stream>>>(Wf1, bf1, Wf2, bf2, mean2, mean1, filt1, filt2);
  k_final<<<4, 256, 0, stream>>>(acct1, acct2, filt1, filt2, out);
}